// Round 1
// baseline (295.137 us; speedup 1.0000x reference)
//
#include <hip/hip_runtime.h>

#define SEQ   2048
#define CZ    64
#define VBINS (2 * (SEQ - 1) + 1)   // 4095

// ---------------------------------------------------------------------------
// Pass 1: T[r][c] = W[c][r] + bias[c]   (transposed, bias-fused table)
// T is VBINS x CZ f32  ~= 1 MiB. Reads of W are strided (transpose) but W is
// only 1 MiB -> L2-resident; this pass is negligible.
// ---------------------------------------------------------------------------
__global__ void build_table_kernel(const float* __restrict__ W,
                                   const float* __restrict__ bias,
                                   float* __restrict__ T) {
    int idx = blockIdx.x * blockDim.x + threadIdx.x;   // over r*CZ + c
    const int total = VBINS * CZ;
    if (idx < total) {
        int r = idx >> 6;       // idx / CZ
        int c = idx & 63;       // idx % CZ
        T[idx] = W[c * VBINS + r] + bias[c];
    }
}

// ---------------------------------------------------------------------------
// Pass 2: out[(i*SEQ + j)*CZ + c] = T[RI[i,j]*CZ + c]
// One float4 (4 c-values) per thread-iteration; 16 threads cover one (i,j).
// Reads: RI broadcast (4 B per 16 lanes), T rows (256 B contiguous, L2-hit).
// Writes: fully coalesced float4 stream, 1 GiB total -> HBM-write-bound.
// ---------------------------------------------------------------------------
__global__ void gather_table_kernel(const int* __restrict__ RI,
                                    const float* __restrict__ T,
                                    float4* __restrict__ out) {
    const long long total = (long long)SEQ * SEQ * (CZ / 4);   // float4 count
    long long idx    = (long long)blockIdx.x * blockDim.x + threadIdx.x;
    long long stride = (long long)gridDim.x * blockDim.x;
    for (; idx < total; idx += stride) {
        int ij = (int)(idx >> 4);          // which (i,j) pair
        int q  = (int)(idx & 15);          // which float4 within the 64 c's
        int r  = RI[ij];
        out[idx] = *reinterpret_cast<const float4*>(T + (long long)r * CZ + (q << 2));
    }
}

// ---------------------------------------------------------------------------
// Fallback (if d_ws too small for the 1 MiB table): gather directly from W
// (transposed access, L2-hit after warm) with inline bias add.
// ---------------------------------------------------------------------------
__global__ void gather_direct_kernel(const int* __restrict__ RI,
                                     const float* __restrict__ W,
                                     const float* __restrict__ bias,
                                     float4* __restrict__ out) {
    const long long total = (long long)SEQ * SEQ * (CZ / 4);
    long long idx    = (long long)blockIdx.x * blockDim.x + threadIdx.x;
    long long stride = (long long)gridDim.x * blockDim.x;
    for (; idx < total; idx += stride) {
        int ij = (int)(idx >> 4);
        int q  = (int)(idx & 15);
        int r  = RI[ij];
        int c0 = q << 2;
        float4 v;
        v.x = W[(c0 + 0) * VBINS + r] + bias[c0 + 0];
        v.y = W[(c0 + 1) * VBINS + r] + bias[c0 + 1];
        v.z = W[(c0 + 2) * VBINS + r] + bias[c0 + 2];
        v.w = W[(c0 + 3) * VBINS + r] + bias[c0 + 3];
        out[idx] = v;
    }
}

extern "C" void kernel_launch(void* const* d_in, const int* in_sizes, int n_in,
                              void* d_out, int out_size, void* d_ws, size_t ws_size,
                              hipStream_t stream) {
    const int*   RI   = (const int*)d_in[0];     // (SEQ, SEQ) int32
    const float* W    = (const float*)d_in[1];   // (CZ, VBINS) f32
    const float* bias = (const float*)d_in[2];   // (CZ,) f32
    float*       out  = (float*)d_out;           // (SEQ, SEQ, CZ) f32

    const size_t table_bytes = (size_t)VBINS * CZ * sizeof(float);

    // Memory-bound streaming kernel: cap grid ~2048 blocks, grid-stride rest.
    const int block = 256;
    const int grid  = 2048;

    if (ws_size >= table_bytes) {
        float* T = (float*)d_ws;
        const int total1 = VBINS * CZ;
        build_table_kernel<<<(total1 + block - 1) / block, block, 0, stream>>>(W, bias, T);
        gather_table_kernel<<<grid, block, 0, stream>>>(RI, T, (float4*)out);
    } else {
        gather_direct_kernel<<<grid, block, 0, stream>>>(RI, W, bias, (float4*)out);
    }
}

// Round 2
// 233.400 us; speedup vs baseline: 1.2645x; 1.2645x over previous
//
#include <hip/hip_runtime.h>

#define SEQ   2048
#define CZ    64
#define VBINS (2 * (SEQ - 1) + 1)   // 4095

typedef float f32x4 __attribute__((ext_vector_type(4)));

// ---------------------------------------------------------------------------
// Pass 1: T[r][c] = W[c][r] + bias[c]   (transposed, bias-fused table)
// T is VBINS x CZ f32 ~= 1 MiB. Negligible cost; W is L2-resident.
// ---------------------------------------------------------------------------
__global__ void build_table_kernel(const float* __restrict__ W,
                                   const float* __restrict__ bias,
                                   float* __restrict__ T) {
    int idx = blockIdx.x * blockDim.x + threadIdx.x;   // over r*CZ + c
    const int total = VBINS * CZ;
    if (idx < total) {
        int r = idx >> 6;       // idx / CZ
        int c = idx & 63;       // idx % CZ
        T[idx] = W[c * VBINS + r] + bias[c];
    }
}

// ---------------------------------------------------------------------------
// Pass 2: out[(i*SEQ + j)*CZ + c] = T[RI[i,j]*CZ + c]
// float4 per thread-iteration; 16 threads cover one (i,j).
// Unroll-by-4 phase-split: 4 independent RI loads -> 4 T loads -> 4 NT stores.
// Hides the RI->T dependent-chain latency (4 chains in flight / thread).
// Nontemporal stores keep the 1 GiB output stream from thrashing L2, so the
// 1 MiB table stays resident.
// ---------------------------------------------------------------------------
__global__ void gather_table_kernel(const int* __restrict__ RI,
                                    const float* __restrict__ T,
                                    float* __restrict__ out) {
    const long long total = (long long)SEQ * SEQ * (CZ / 4);   // 67,108,864 float4
    const long long stride = (long long)gridDim.x * blockDim.x;
    long long idx = (long long)blockIdx.x * blockDim.x + threadIdx.x;

    // Main unrolled loop: with grid=2048x256, total/stride = 128 exactly
    // (32 rounds of unroll-4, no remainder). Tail loop kept for safety.
    for (; idx + 3 * stride < total; idx += 4 * stride) {
        const long long i0 = idx;
        const long long i1 = idx + stride;
        const long long i2 = idx + 2 * stride;
        const long long i3 = idx + 3 * stride;

        // Phase 1: 4 independent index loads
        const int r0 = RI[(int)(i0 >> 4)];
        const int r1 = RI[(int)(i1 >> 4)];
        const int r2 = RI[(int)(i2 >> 4)];
        const int r3 = RI[(int)(i3 >> 4)];

        // Phase 2: 4 independent table loads (L1/L2 hit; rows are contiguous
        // for consecutive ij, so locality is excellent)
        const f32x4 v0 = *reinterpret_cast<const f32x4*>(T + r0 * CZ + (((int)i0 & 15) << 2));
        const f32x4 v1 = *reinterpret_cast<const f32x4*>(T + r1 * CZ + (((int)i1 & 15) << 2));
        const f32x4 v2 = *reinterpret_cast<const f32x4*>(T + r2 * CZ + (((int)i2 & 15) << 2));
        const f32x4 v3 = *reinterpret_cast<const f32x4*>(T + r3 * CZ + (((int)i3 & 15) << 2));

        // Phase 3: 4 coalesced nontemporal float4 stores (1 KiB/wave each)
        __builtin_nontemporal_store(v0, reinterpret_cast<f32x4*>(out) + i0);
        __builtin_nontemporal_store(v1, reinterpret_cast<f32x4*>(out) + i1);
        __builtin_nontemporal_store(v2, reinterpret_cast<f32x4*>(out) + i2);
        __builtin_nontemporal_store(v3, reinterpret_cast<f32x4*>(out) + i3);
    }
    for (; idx < total; idx += stride) {
        const int r = RI[(int)(idx >> 4)];
        const f32x4 v = *reinterpret_cast<const f32x4*>(T + r * CZ + (((int)idx & 15) << 2));
        __builtin_nontemporal_store(v, reinterpret_cast<f32x4*>(out) + idx);
    }
}

// ---------------------------------------------------------------------------
// Fallback (if d_ws too small for the 1 MiB table): gather directly from W.
// ---------------------------------------------------------------------------
__global__ void gather_direct_kernel(const int* __restrict__ RI,
                                     const float* __restrict__ W,
                                     const float* __restrict__ bias,
                                     float* __restrict__ out) {
    const long long total = (long long)SEQ * SEQ * (CZ / 4);
    const long long stride = (long long)gridDim.x * blockDim.x;
    long long idx = (long long)blockIdx.x * blockDim.x + threadIdx.x;
    for (; idx < total; idx += stride) {
        int ij = (int)(idx >> 4);
        int q  = (int)(idx & 15);
        int r  = RI[ij];
        int c0 = q << 2;
        f32x4 v;
        v.x = W[(c0 + 0) * VBINS + r] + bias[c0 + 0];
        v.y = W[(c0 + 1) * VBINS + r] + bias[c0 + 1];
        v.z = W[(c0 + 2) * VBINS + r] + bias[c0 + 2];
        v.w = W[(c0 + 3) * VBINS + r] + bias[c0 + 3];
        __builtin_nontemporal_store(v, reinterpret_cast<f32x4*>(out) + idx);
    }
}

extern "C" void kernel_launch(void* const* d_in, const int* in_sizes, int n_in,
                              void* d_out, int out_size, void* d_ws, size_t ws_size,
                              hipStream_t stream) {
    const int*   RI   = (const int*)d_in[0];     // (SEQ, SEQ) int32
    const float* W    = (const float*)d_in[1];   // (CZ, VBINS) f32
    const float* bias = (const float*)d_in[2];   // (CZ,) f32
    float*       out  = (float*)d_out;           // (SEQ, SEQ, CZ) f32

    const size_t table_bytes = (size_t)VBINS * CZ * sizeof(float);

    const int block = 256;
    const int grid  = 2048;   // 32 waves/CU on 256 CUs; 128 iters/thread

    if (ws_size >= table_bytes) {
        float* T = (float*)d_ws;
        const int total1 = VBINS * CZ;
        build_table_kernel<<<(total1 + block - 1) / block, block, 0, stream>>>(W, bias, T);
        gather_table_kernel<<<grid, block, 0, stream>>>(RI, T, out);
    } else {
        gather_direct_kernel<<<grid, block, 0, stream>>>(RI, W, bias, out);
    }
}

// Round 3
// 210.317 us; speedup vs baseline: 1.4033x; 1.1098x over previous
//
#include <hip/hip_runtime.h>

#define SEQ   2048
#define CZ    64
#define VBINS (2 * (SEQ - 1) + 1)   // 4095

typedef float f32x4 __attribute__((ext_vector_type(4)));

// ---------------------------------------------------------------------------
// Pass 1: T[r][c] = W[c][r] + bias[c]   (transposed, bias-fused table)
// T is VBINS x CZ f32 ~= 1 MiB. Negligible cost; W is L2-resident.
// ---------------------------------------------------------------------------
__global__ void build_table_kernel(const float* __restrict__ W,
                                   const float* __restrict__ bias,
                                   float* __restrict__ T) {
    int idx = blockIdx.x * blockDim.x + threadIdx.x;   // over r*CZ + c
    const int total = VBINS * CZ;
    if (idx < total) {
        int r = idx >> 6;       // idx / CZ
        int c = idx & 63;       // idx % CZ
        T[idx] = W[c * VBINS + r] + bias[c];
    }
}

// ---------------------------------------------------------------------------
// Pass 2: out[i, :, :] = T_flat[RI[i,0]*CZ : RI[i,0]*CZ + SEQ*CZ]
// Rel-pos structure: RI[i,j] = RI[i,0] + j, so each output row is one
// contiguous 512 KiB slice of the fused table. Pure stream copy:
//   - one block per row i; rbase = RI[i,0] read once (wave-uniform s_load)
//   - reads: contiguous float4 from the L2-resident 1 MiB table
//   - writes: nontemporal float4 stream (don't thrash L2)
// No per-element indirection, no dependent chains in the hot loop.
// ---------------------------------------------------------------------------
__global__ void copy_rows_kernel(const int* __restrict__ RI,
                                 const float* __restrict__ T,
                                 float* __restrict__ out) {
    const int i = blockIdx.x;                      // output row
    const int rbase = RI[(long long)i << 11];      // RI[i][0]  (uniform)
    const f32x4* __restrict__ src = reinterpret_cast<const f32x4*>(T) + ((long long)rbase << 4);
    f32x4* __restrict__ dst       = reinterpret_cast<f32x4*>(out)     + ((long long)i << 15);

    const int N = SEQ * CZ / 4;                    // 32768 float4 per row
    // 256 threads, unroll-4 phase-split: 32 exact iterations.
    for (int off = threadIdx.x; off < N; off += 4 * 256) {
        const f32x4 v0 = src[off];
        const f32x4 v1 = src[off + 256];
        const f32x4 v2 = src[off + 512];
        const f32x4 v3 = src[off + 768];
        __builtin_nontemporal_store(v0, dst + off);
        __builtin_nontemporal_store(v1, dst + off + 256);
        __builtin_nontemporal_store(v2, dst + off + 512);
        __builtin_nontemporal_store(v3, dst + off + 768);
    }
}

// ---------------------------------------------------------------------------
// Fallback (if d_ws too small for the 1 MiB table): per-element gather from W
// with inline bias add. Still row-structured via rbase.
// ---------------------------------------------------------------------------
__global__ void gather_direct_kernel(const int* __restrict__ RI,
                                     const float* __restrict__ W,
                                     const float* __restrict__ bias,
                                     float* __restrict__ out) {
    const long long total = (long long)SEQ * SEQ * (CZ / 4);
    const long long stride = (long long)gridDim.x * blockDim.x;
    long long idx = (long long)blockIdx.x * blockDim.x + threadIdx.x;
    for (; idx < total; idx += stride) {
        int ij = (int)(idx >> 4);
        int q  = (int)(idx & 15);
        int r  = RI[ij];
        int c0 = q << 2;
        f32x4 v;
        v.x = W[(c0 + 0) * VBINS + r] + bias[c0 + 0];
        v.y = W[(c0 + 1) * VBINS + r] + bias[c0 + 1];
        v.z = W[(c0 + 2) * VBINS + r] + bias[c0 + 2];
        v.w = W[(c0 + 3) * VBINS + r] + bias[c0 + 3];
        __builtin_nontemporal_store(v, reinterpret_cast<f32x4*>(out) + idx);
    }
}

extern "C" void kernel_launch(void* const* d_in, const int* in_sizes, int n_in,
                              void* d_out, int out_size, void* d_ws, size_t ws_size,
                              hipStream_t stream) {
    const int*   RI   = (const int*)d_in[0];     // (SEQ, SEQ) int32
    const float* W    = (const float*)d_in[1];   // (CZ, VBINS) f32
    const float* bias = (const float*)d_in[2];   // (CZ,) f32
    float*       out  = (float*)d_out;           // (SEQ, SEQ, CZ) f32

    const size_t table_bytes = (size_t)VBINS * CZ * sizeof(float);
    const int block = 256;

    if (ws_size >= table_bytes) {
        float* T = (float*)d_ws;
        const int total1 = VBINS * CZ;
        build_table_kernel<<<(total1 + block - 1) / block, block, 0, stream>>>(W, bias, T);
        copy_rows_kernel<<<SEQ, block, 0, stream>>>(RI, T, out);   // 1 block per row
    } else {
        gather_direct_kernel<<<2048, block, 0, stream>>>(RI, W, bias, out);
    }
}

// Round 4
// 205.022 us; speedup vs baseline: 1.4395x; 1.0258x over previous
//
#include <hip/hip_runtime.h>

#define SEQ   2048
#define CZ    64
#define VBINS (2 * (SEQ - 1) + 1)   // 4095

typedef float f32x4 __attribute__((ext_vector_type(4)));

// ---------------------------------------------------------------------------
// Pass 1: T[r][c] = W[c][r] + bias[c]   (transposed, bias-fused table)
// T is VBINS x CZ f32 ~= 1 MiB. Negligible cost; W is L2-resident.
// ---------------------------------------------------------------------------
__global__ void build_table_kernel(const float* __restrict__ W,
                                   const float* __restrict__ bias,
                                   float* __restrict__ T) {
    int idx = blockIdx.x * blockDim.x + threadIdx.x;   // over r*CZ + c
    const int total = VBINS * CZ;
    if (idx < total) {
        int r = idx >> 6;       // idx / CZ
        int c = idx & 63;       // idx % CZ
        T[idx] = W[c * VBINS + r] + bias[c];
    }
}

// ---------------------------------------------------------------------------
// Pass 2: out[i, :, :] = T_flat[RI[i,0]*CZ : RI[i,0]*CZ + SEQ*CZ]
// One block per row. Ping-pong double-buffered stream copy: while storing
// buffer A (4 float4/thread), buffer B's 4 loads are already in flight, so
// the store phase never waits on a fresh L2 round-trip. NT stores keep the
// 1 GiB output stream out of L2 (table stays resident).
// __launch_bounds__(256,8): pin VGPR <= 64 so occupancy stays 32 waves/CU.
// ---------------------------------------------------------------------------
__global__ void __launch_bounds__(256, 8)
copy_rows_kernel(const int* __restrict__ RI,
                 const float* __restrict__ T,
                 float* __restrict__ out) {
    const int i = blockIdx.x;                      // output row
    const int rbase = RI[(long long)i << 11];      // RI[i][0]  (uniform)
    const f32x4* __restrict__ src = reinterpret_cast<const f32x4*>(T) + ((long long)rbase << 4);
    f32x4* __restrict__ dst       = reinterpret_cast<f32x4*>(out)     + ((long long)i << 15);

    constexpr int THREADS = 256;
    constexpr int U       = 4;                     // float4 per phase per thread
    constexpr int CHUNK   = U * THREADS;           // 1024 float4 per phase
    constexpr int N       = SEQ * CZ / 4;          // 32768 float4 per row
    constexpr int NIT     = N / CHUNK;             // 32 phases (even)

    const int tid = threadIdx.x;

    f32x4 a[U], b[U];

    // Prologue: load phase 0 into A.
    #pragma unroll
    for (int u = 0; u < U; ++u) a[u] = src[tid + u * THREADS];

    // Ping-pong: 16 outer iterations covering phases (2k, 2k+1).
    for (int it = 0; it < NIT; it += 2) {
        const int baseA = it * CHUNK + tid;
        const int baseB = (it + 1) * CHUNK + tid;
        const int baseN = (it + 2) * CHUNK + tid;

        // Load phase it+1 into B, then store A (B's loads stay in flight).
        #pragma unroll
        for (int u = 0; u < U; ++u) b[u] = src[baseB + u * THREADS];
        #pragma unroll
        for (int u = 0; u < U; ++u)
            __builtin_nontemporal_store(a[u], dst + baseA + u * THREADS);

        // Load phase it+2 into A (unless done), then store B.
        if (it + 2 < NIT) {
            #pragma unroll
            for (int u = 0; u < U; ++u) a[u] = src[baseN + u * THREADS];
        }
        #pragma unroll
        for (int u = 0; u < U; ++u)
            __builtin_nontemporal_store(b[u], dst + baseB + u * THREADS);
    }
}

// ---------------------------------------------------------------------------
// Fallback (if d_ws too small for the 1 MiB table): per-element gather from W
// with inline bias add.
// ---------------------------------------------------------------------------
__global__ void gather_direct_kernel(const int* __restrict__ RI,
                                     const float* __restrict__ W,
                                     const float* __restrict__ bias,
                                     float* __restrict__ out) {
    const long long total = (long long)SEQ * SEQ * (CZ / 4);
    const long long stride = (long long)gridDim.x * blockDim.x;
    long long idx = (long long)blockIdx.x * blockDim.x + threadIdx.x;
    for (; idx < total; idx += stride) {
        int ij = (int)(idx >> 4);
        int q  = (int)(idx & 15);
        int r  = RI[ij];
        int c0 = q << 2;
        f32x4 v;
        v.x = W[(c0 + 0) * VBINS + r] + bias[c0 + 0];
        v.y = W[(c0 + 1) * VBINS + r] + bias[c0 + 1];
        v.z = W[(c0 + 2) * VBINS + r] + bias[c0 + 2];
        v.w = W[(c0 + 3) * VBINS + r] + bias[c0 + 3];
        __builtin_nontemporal_store(v, reinterpret_cast<f32x4*>(out) + idx);
    }
}

extern "C" void kernel_launch(void* const* d_in, const int* in_sizes, int n_in,
                              void* d_out, int out_size, void* d_ws, size_t ws_size,
                              hipStream_t stream) {
    const int*   RI   = (const int*)d_in[0];     // (SEQ, SEQ) int32
    const float* W    = (const float*)d_in[1];   // (CZ, VBINS) f32
    const float* bias = (const float*)d_in[2];   // (CZ,) f32
    float*       out  = (float*)d_out;           // (SEQ, SEQ, CZ) f32

    const size_t table_bytes = (size_t)VBINS * CZ * sizeof(float);
    const int block = 256;

    if (ws_size >= table_bytes) {
        float* T = (float*)d_ws;
        const int total1 = VBINS * CZ;
        build_table_kernel<<<(total1 + block - 1) / block, block, 0, stream>>>(W, bias, T);
        copy_rows_kernel<<<SEQ, block, 0, stream>>>(RI, T, out);   // 1 block per row
    } else {
        gather_direct_kernel<<<2048, block, 0, stream>>>(RI, W, bias, out);
    }
}

// Round 5
// 195.819 us; speedup vs baseline: 1.5072x; 1.0470x over previous
//
#include <hip/hip_runtime.h>

#define SEQ   2048
#define CZ    64
#define VBINS (2 * (SEQ - 1) + 1)   // 4095

typedef float f32x4 __attribute__((ext_vector_type(4)));

// ---------------------------------------------------------------------------
// Pass 1: T[r][c] = W[c][r] + bias[c]   (transposed, bias-fused table)
// T is VBINS x CZ f32 ~= 1 MiB. Negligible cost; W is L2-resident.
// ---------------------------------------------------------------------------
__global__ void build_table_kernel(const float* __restrict__ W,
                                   const float* __restrict__ bias,
                                   float* __restrict__ T) {
    int idx = blockIdx.x * blockDim.x + threadIdx.x;   // over r*CZ + c
    const int total = VBINS * CZ;
    if (idx < total) {
        int r = idx >> 6;       // idx / CZ
        int c = idx & 63;       // idx % CZ
        T[idx] = W[c * VBINS + r] + bias[c];
    }
}

// ---------------------------------------------------------------------------
// Pass 2: out[i, :, :] = T_flat[RI[i,0]*CZ : RI[i,0]*CZ + SEQ*CZ]
// One block per row; ping-pong double-buffered stream copy.
// A/B vs round 4: PLAIN stores instead of nontemporal. fillBuffer reaches
// 6.5 TB/s with cached stores (TCC write-combining of full lines); nt may
// bypass that batching. Table eviction by the write stream is absorbed by
// the 256 MiB L3, so losing L2 residency of T costs ~nothing.
// ---------------------------------------------------------------------------
__global__ void __launch_bounds__(256, 8)
copy_rows_kernel(const int* __restrict__ RI,
                 const float* __restrict__ T,
                 float* __restrict__ out) {
    const int i = blockIdx.x;                      // output row
    const int rbase = RI[(long long)i << 11];      // RI[i][0]  (uniform)
    const f32x4* __restrict__ src = reinterpret_cast<const f32x4*>(T) + ((long long)rbase << 4);
    f32x4* __restrict__ dst       = reinterpret_cast<f32x4*>(out)     + ((long long)i << 15);

    constexpr int THREADS = 256;
    constexpr int U       = 4;                     // float4 per phase per thread
    constexpr int CHUNK   = U * THREADS;           // 1024 float4 per phase
    constexpr int N       = SEQ * CZ / 4;          // 32768 float4 per row
    constexpr int NIT     = N / CHUNK;             // 32 phases (even)

    const int tid = threadIdx.x;

    f32x4 a[U], b[U];

    // Prologue: load phase 0 into A.
    #pragma unroll
    for (int u = 0; u < U; ++u) a[u] = src[tid + u * THREADS];

    // Ping-pong: 16 outer iterations covering phases (2k, 2k+1).
    for (int it = 0; it < NIT; it += 2) {
        const int baseA = it * CHUNK + tid;
        const int baseB = (it + 1) * CHUNK + tid;
        const int baseN = (it + 2) * CHUNK + tid;

        // Load phase it+1 into B, then store A (B's loads stay in flight).
        #pragma unroll
        for (int u = 0; u < U; ++u) b[u] = src[baseB + u * THREADS];
        #pragma unroll
        for (int u = 0; u < U; ++u) dst[baseA + u * THREADS] = a[u];

        // Load phase it+2 into A (unless done), then store B.
        if (it + 2 < NIT) {
            #pragma unroll
            for (int u = 0; u < U; ++u) a[u] = src[baseN + u * THREADS];
        }
        #pragma unroll
        for (int u = 0; u < U; ++u) dst[baseB + u * THREADS] = b[u];
    }
}

// ---------------------------------------------------------------------------
// Fallback (if d_ws too small for the 1 MiB table): per-element gather from W
// with inline bias add.
// ---------------------------------------------------------------------------
__global__ void gather_direct_kernel(const int* __restrict__ RI,
                                     const float* __restrict__ W,
                                     const float* __restrict__ bias,
                                     float* __restrict__ out) {
    const long long total = (long long)SEQ * SEQ * (CZ / 4);
    const long long stride = (long long)gridDim.x * blockDim.x;
    long long idx = (long long)blockIdx.x * blockDim.x + threadIdx.x;
    for (; idx < total; idx += stride) {
        int ij = (int)(idx >> 4);
        int q  = (int)(idx & 15);
        int r  = RI[ij];
        int c0 = q << 2;
        f32x4 v;
        v.x = W[(c0 + 0) * VBINS + r] + bias[c0 + 0];
        v.y = W[(c0 + 1) * VBINS + r] + bias[c0 + 1];
        v.z = W[(c0 + 2) * VBINS + r] + bias[c0 + 2];
        v.w = W[(c0 + 3) * VBINS + r] + bias[c0 + 3];
        reinterpret_cast<f32x4*>(out)[idx] = v;
    }
}

extern "C" void kernel_launch(void* const* d_in, const int* in_sizes, int n_in,
                              void* d_out, int out_size, void* d_ws, size_t ws_size,
                              hipStream_t stream) {
    const int*   RI   = (const int*)d_in[0];     // (SEQ, SEQ) int32
    const float* W    = (const float*)d_in[1];   // (CZ, VBINS) f32
    const float* bias = (const float*)d_in[2];   // (CZ,) f32
    float*       out  = (float*)d_out;           // (SEQ, SEQ, CZ) f32

    const size_t table_bytes = (size_t)VBINS * CZ * sizeof(float);
    const int block = 256;

    if (ws_size >= table_bytes) {
        float* T = (float*)d_ws;
        const int total1 = VBINS * CZ;
        build_table_kernel<<<(total1 + block - 1) / block, block, 0, stream>>>(W, bias, T);
        copy_rows_kernel<<<SEQ, block, 0, stream>>>(RI, T, out);   // 1 block per row
    } else {
        gather_direct_kernel<<<2048, block, 0, stream>>>(RI, W, bias, out);
    }
}

// Round 6
// 192.867 us; speedup vs baseline: 1.5303x; 1.0153x over previous
//
#include <hip/hip_runtime.h>

#define SEQ   2048
#define CZ    64
#define VBINS (2 * (SEQ - 1) + 1)   // 4095

typedef float f32x4 __attribute__((ext_vector_type(4)));

// ---------------------------------------------------------------------------
// Pass 1: T[r][c] = W[c][r] + bias[c]   (transposed, bias-fused table)
// T is VBINS x CZ f32 ~= 1 MiB. Negligible cost; W is L2-resident.
// ---------------------------------------------------------------------------
__global__ void build_table_kernel(const float* __restrict__ W,
                                   const float* __restrict__ bias,
                                   float* __restrict__ T) {
    int idx = blockIdx.x * blockDim.x + threadIdx.x;   // over r*CZ + c
    const int total = VBINS * CZ;
    if (idx < total) {
        int r = idx >> 6;       // idx / CZ
        int c = idx & 63;       // idx % CZ
        T[idx] = W[c * VBINS + r] + bias[c];
    }
}

// ---------------------------------------------------------------------------
// Pass 2: out[i, :, :] = T_flat[RI[i,0]*CZ : RI[i,0]*CZ + SEQ*CZ]
// One block per row. A/B vs round 5: U=8 single-buffered (8 loads in flight
// -> one waitcnt -> 8 stores) instead of U=4 ping-pong. Halves the number of
// vmcnt drain points (16 iters vs 32) and doubles per-wave MLP. Plain cached
// stores (NT measured -10 us worse). VGPR ~48, occupancy stays 32 waves/CU.
// ---------------------------------------------------------------------------
__global__ void __launch_bounds__(256, 8)
copy_rows_kernel(const int* __restrict__ RI,
                 const float* __restrict__ T,
                 float* __restrict__ out) {
    const int i = blockIdx.x;                      // output row
    const int rbase = RI[(long long)i << 11];      // RI[i][0]  (uniform)
    const f32x4* __restrict__ src = reinterpret_cast<const f32x4*>(T) + ((long long)rbase << 4);
    f32x4* __restrict__ dst       = reinterpret_cast<f32x4*>(out)     + ((long long)i << 15);

    constexpr int THREADS = 256;
    constexpr int U       = 8;                     // float4 per phase per thread
    constexpr int CHUNK   = U * THREADS;           // 2048 float4 per phase
    constexpr int N       = SEQ * CZ / 4;          // 32768 float4 per row
    constexpr int NIT     = N / CHUNK;             // 16 phases

    const int tid = threadIdx.x;
    f32x4 a[U];

    for (int it = 0; it < NIT; ++it) {
        const int base = it * CHUNK + tid;
        #pragma unroll
        for (int u = 0; u < U; ++u) a[u] = src[base + u * THREADS];
        #pragma unroll
        for (int u = 0; u < U; ++u) dst[base + u * THREADS] = a[u];
    }
}

// ---------------------------------------------------------------------------
// Fallback (if d_ws too small for the 1 MiB table): per-element gather from W
// with inline bias add.
// ---------------------------------------------------------------------------
__global__ void gather_direct_kernel(const int* __restrict__ RI,
                                     const float* __restrict__ W,
                                     const float* __restrict__ bias,
                                     float* __restrict__ out) {
    const long long total = (long long)SEQ * SEQ * (CZ / 4);
    const long long stride = (long long)gridDim.x * blockDim.x;
    long long idx = (long long)blockIdx.x * blockDim.x + threadIdx.x;
    for (; idx < total; idx += stride) {
        int ij = (int)(idx >> 4);
        int q  = (int)(idx & 15);
        int r  = RI[ij];
        int c0 = q << 2;
        f32x4 v;
        v.x = W[(c0 + 0) * VBINS + r] + bias[c0 + 0];
        v.y = W[(c0 + 1) * VBINS + r] + bias[c0 + 1];
        v.z = W[(c0 + 2) * VBINS + r] + bias[c0 + 2];
        v.w = W[(c0 + 3) * VBINS + r] + bias[c0 + 3];
        reinterpret_cast<f32x4*>(out)[idx] = v;
    }
}

extern "C" void kernel_launch(void* const* d_in, const int* in_sizes, int n_in,
                              void* d_out, int out_size, void* d_ws, size_t ws_size,
                              hipStream_t stream) {
    const int*   RI   = (const int*)d_in[0];     // (SEQ, SEQ) int32
    const float* W    = (const float*)d_in[1];   // (CZ, VBINS) f32
    const float* bias = (const float*)d_in[2];   // (CZ,) f32
    float*       out  = (float*)d_out;           // (SEQ, SEQ, CZ) f32

    const size_t table_bytes = (size_t)VBINS * CZ * sizeof(float);
    const int block = 256;

    if (ws_size >= table_bytes) {
        float* T = (float*)d_ws;
        const int total1 = VBINS * CZ;
        build_table_kernel<<<(total1 + block - 1) / block, block, 0, stream>>>(W, bias, T);
        copy_rows_kernel<<<SEQ, block, 0, stream>>>(RI, T, out);   // 1 block per row
    } else {
        gather_direct_kernel<<<2048, block, 0, stream>>>(RI, W, bias, out);
    }
}